// Round 2
// baseline (217.074 us; speedup 1.0000x reference)
//
#include <hip/hip_runtime.h>

#define NN   24000
#define NTP  8000
#define HH   8
#define DKK  16
#define RR   34
#define EPRN 10000
#define NE   (RR*EPRN)     // 340000
#define NB   (RR*NTP)      // 272000 buckets (r, dst_local)
#define CAP  16            // fixed bucket capacity; P(cnt>=16 | Poisson 1.25) ~ 1e-12
#define NSCAT ((NE+255)/256)   // 1329 scatter blocks
#define NPAIR 17
#define LOG2E 1.4426950408889634f

typedef short short8 __attribute__((ext_vector_type(8)));
typedef _Float16 half8 __attribute__((ext_vector_type(8)));
typedef float f32x4  __attribute__((ext_vector_type(4)));
typedef _Float16 h2v __attribute__((ext_vector_type(2)));

#if defined(__has_builtin)
# if __has_builtin(__builtin_amdgcn_fdot2)
#  define USE_FDOT2 1
# endif
#endif
#ifndef USE_FDOT2
# define USE_FDOT2 0
#endif

__device__ __forceinline__ int src_nt(int r){ return r<=9?0:(r<=21?1:2); }
__device__ __forceinline__ int dst_nt(int r){
    if (r<=2)  return 0;
    if (r<=6)  return 1;
    if (r<=9)  return 2;
    if (r<=13) return 0;
    if (r<=17) return 1;
    if (r<=21) return 2;
    if (r<=24) return 0;
    if (r<=28) return 1;
    return 2;
}

// relation pairs per dtau (dst type): counts 10/12/12 -> 5/6/6 pairs, all even.
__device__ const int PAIRS[NPAIR][2] = {
    {0,1},{2,10},{11,12},{13,22},{23,24},          // dtau 0
    {3,4},{5,6},{14,15},{16,17},{25,26},{27,28},   // dtau 1
    {7,8},{9,18},{19,20},{21,29},{30,31},{32,33}}; // dtau 2
__device__ const int PBASE[3] = {0,5,11};
__device__ const int PCNT[3]  = {5,6,6};

__device__ __forceinline__ unsigned short bf16rne(float a){
    unsigned int u = __float_as_uint(a);
    u += 0x7fffu + ((u >> 16) & 1u);
    return (unsigned short)(u >> 16);
}
__device__ __forceinline__ unsigned int bf2pack(float a, float b){
    unsigned int ua = __float_as_uint(a);
    unsigned int ub = __float_as_uint(b);
    ua += 0x7fffu + ((ua >> 16) & 1u);
    ub += 0x7fffu + ((ub >> 16) & 1u);
    return (ua >> 16) | (ub & 0xffff0000u);
}
__device__ __forceinline__ unsigned short f16bits(float a){
    _Float16 h = (_Float16)a;
    return __builtin_bit_cast(unsigned short, h);
}

// ---------------- K0: prep — zero counts + W B-frags + rel_att/rel_msg f16 B-frags
// wfrag tiles 0..287: t = ((tau*3+mat)*8+n)*4+s  (mat: 0=k,1=q,2=v); 288..383: Wa.
// fragAtt[rh][512]: B[k][n] = rel_att[r][h][n][k] for k<16, 0 for k>=16 (Aq MFMA).
// fragMsgP[ph][512]: pair (ra,rb): rows 0..15 = Mra[d][f], rows 16..31 = Mrb[d][f].
__global__ __launch_bounds__(256) void prep_kernel(
    const float* __restrict__ Wk, const float* __restrict__ Wq,
    const float* __restrict__ Wv, const float* __restrict__ Wa,
    const float* __restrict__ rel_att, const float* __restrict__ rel_msg,
    int* __restrict__ counts, unsigned short* __restrict__ wfrag,
    unsigned short* __restrict__ fragAtt, unsigned short* __restrict__ fragMsgP)
{
    const int gid = blockIdx.x * 256 + threadIdx.x;
    if (gid < NB) counts[gid] = 0;
    const int wv   = threadIdx.x >> 6;
    const int lane = threadIdx.x & 63;
    const int m16  = lane & 15, quad = lane >> 4;
    if (blockIdx.x < 96) {
        const int tile = blockIdx.x * 4 + wv;   // 0..383
        const float* W;
        int s, n;
        if (tile < 288) {
            s = tile & 3;
            n = (tile >> 2) & 7;
            const int mat = (tile >> 5) % 3;
            const int tau = tile / 96;
            W = (mat == 0 ? Wk : (mat == 1 ? Wq : Wv)) + (size_t)tau * 16384;
        } else {
            const int t2 = tile - 288;
            s = t2 & 3;
            n = (t2 >> 2) & 7;
            const int tau = t2 >> 5;
            W = Wa + (size_t)tau * 16384;
        }
        const int k0  = s * 32 + quad * 8;
        const int col = n * 16 + m16;
        unsigned short* dstp = wfrag + (size_t)tile * 512 + lane * 8;
        #pragma unroll
        for (int i = 0; i < 8; i++)
            dstp[i] = bf16rne(W[(size_t)(k0 + i) * 128 + col]);
    } else if (blockIdx.x < 164) {
        const int rh = (blockIdx.x - 96) * 4 + wv;   // 0..271
        half8 v;
        #pragma unroll
        for (int i = 0; i < 8; i++) v[i] = (_Float16)0.f;
        if (quad < 2) {
            const float* p = rel_att + ((size_t)rh << 8) + m16 * 16 + quad * 8;
            #pragma unroll
            for (int i = 0; i < 8; i++) v[i] = (_Float16)p[i];
        }
        *(half8*)(fragAtt + ((size_t)rh << 9) + lane * 8) = v;
    } else if (blockIdx.x < 198) {
        const int ph = (blockIdx.x - 164) * 4 + wv;  // 0..135
        const int pair = ph >> 3, hh = ph & 7;
        const int r  = (quad < 2) ? PAIRS[pair][0] : PAIRS[pair][1];
        const int kk = (quad & 1) * 8;               // d base within its sub-matrix
        const float* Mp = rel_msg + (((size_t)r * HH + hh) << 8);
        half8 v;
        #pragma unroll
        for (int i = 0; i < 8; i++) v[i] = (_Float16)Mp[(kk + i) * 16 + m16];
        *(half8*)(fragMsgP + ((size_t)ph << 9) + lane * 8) = v;
    }
}

// ---------------- K1: merged qkv-MFMA + edge scatter + qwq/kwk precompute ------
__global__ __launch_bounds__(256) void work1(
    const float* __restrict__ x,
    const float* __restrict__ bk, const float* __restrict__ bq,
    const float* __restrict__ bv,
    const unsigned short* __restrict__ wfrag,
    const int* __restrict__ src, const int* __restrict__ dst,
    int* __restrict__ counts, int* __restrict__ esrc16,
    float* __restrict__ qo, unsigned short* __restrict__ kvh,
    const float* __restrict__ attn_w,
    float* __restrict__ qwqA, float* __restrict__ kwkA)
{
    __shared__ float qs[4][16][132];
    __shared__ unsigned short ksh[4][16][264];

    if (blockIdx.x >= 375) {        // ---- scatter part ----
        int e = (blockIdx.x - 375) * 256 + threadIdx.x;
        if (e < NE) {
            int r = e / EPRN;
            int b = r * NTP + (dst[e] - dst_nt(r) * NTP);
            int pos = atomicAdd(&counts[b], 1);
            if (pos < CAP) esrc16[(size_t)b * CAP + pos] = src[e];
        }
        return;
    }

    // ---- qkv part ----
    const int rb   = blockIdx.x * 64;
    const int tau  = rb / NTP;          // 8000 % 64 == 0 -> uniform
    const int w    = threadIdx.x >> 6;
    const int lane = threadIdx.x & 63;
    const int m    = lane & 15;
    const int quad = lane >> 4;

    short8 af[4];
    {
        const float* xrow = x + (size_t)(rb + w * 16 + m) * 128;
        #pragma unroll
        for (int s = 0; s < 4; s++) {
            float4 f0 = *(const float4*)(xrow + s * 32 + quad * 8);
            float4 f1 = *(const float4*)(xrow + s * 32 + quad * 8 + 4);
            union { unsigned int u[4]; short8 v; } pk;
            pk.u[0] = bf2pack(f0.x, f0.y); pk.u[1] = bf2pack(f0.z, f0.w);
            pk.u[2] = bf2pack(f1.x, f1.y); pk.u[3] = bf2pack(f1.z, f1.w);
            af[s] = pk.v;
        }
    }

    #pragma unroll
    for (int mat = 0; mat < 3; mat++) {
        const float* bias = (mat == 0 ? bk : (mat == 1 ? bq : bv)) + tau * 128;
        #pragma unroll
        for (int n = 0; n < 8; n++) {
            float bb = bias[n * 16 + m];
            f32x4 acc = {bb, bb, bb, bb};
            #pragma unroll
            for (int s = 0; s < 4; s++) {
                const int tile = ((tau * 3 + mat) * 8 + n) * 4 + s;
                short8 bf = *(const short8*)(wfrag + (size_t)tile * 512 + lane * 8);
                acc = __builtin_amdgcn_mfma_f32_16x16x32_bf16(af[s], bf, acc, 0, 0, 0);
            }
            if (mat == 1) {
                #pragma unroll
                for (int i = 0; i < 4; i++) qs[w][quad * 4 + i][n * 16 + m] = acc[i];
            } else {
                const int off = n * 32 + (mat == 0 ? 0 : 16) + m;
                #pragma unroll
                for (int i = 0; i < 4; i++) ksh[w][quad * 4 + i][off] = f16bits(acc[i]);
            }
        }
        if (mat == 1) {
            __syncthreads();
            #pragma unroll
            for (int j = 0; j < 8; j++) {
                const int id = lane + 64 * j;
                const int row = id >> 5, c4 = id & 31;
                float4 v = *(const float4*)(&qs[w][row][c4 * 4]);
                *(float4*)(qo + (size_t)(rb + w * 16 + row) * 128 + c4 * 4) = v;
            }
        }
    }
    __syncthreads();
    #pragma unroll
    for (int j = 0; j < 8; j++) {
        const int id = lane + 64 * j;
        const int row = id >> 5, c8 = id & 31;
        uint4 u = *(const uint4*)(&ksh[w][row][c8 * 8]);
        *(uint4*)(kvh + (size_t)(rb + w * 16 + row) * 256 + c8 * 8) = u;
    }
    // epilogue: node-level qwq = q . wq, kwk = k . wk (per head) from LDS
    #pragma unroll
    for (int rep = 0; rep < 2; rep++) {
        const int idx = threadIdx.x + rep * 256;     // 0..511 = 64 rows x 8 heads
        const int row = idx >> 3, hh = idx & 7;
        const float* qrow = &qs[row >> 4][row & 15][hh * 16];
        const unsigned short* krow = &ksh[row >> 4][row & 15][hh * 32];
        float sq = 0.f, sk = 0.f;
        #pragma unroll
        for (int f = 0; f < 16; f++) {
            sq += qrow[f] * attn_w[f];
            sk += (float)__builtin_bit_cast(_Float16, krow[f]) * attn_w[16 + f];
        }
        qwqA[(size_t)(rb + row) * 8 + hh] = sq;
        kwkA[(size_t)(rb + row) * 8 + hh] = sk;
    }
}

// ---------------- K2: fused edge phase — Aq and rel_msg apply via f16 MFMA ------
// wave = 64 dst nodes x 1 head. Per relation: Aq = (64x16 q)x(16x16 A^T) as 4
// mfma_f32_16x16x32_f16 (K upper half zero), transposed back per-lane via
// wave-private LDS (no barriers). rel_msg applied per relation-PAIR with K=32
// fully used (md of 2 relations stacked). Scores use exp2 with folded log2e.
__global__ __launch_bounds__(256) void edge_fused(
    const float* __restrict__ q, const unsigned short* __restrict__ kvh,
    const int* __restrict__ esrc16, const int* __restrict__ counts,
    const unsigned short* __restrict__ fragAtt,
    const unsigned short* __restrict__ fragMsgP,
    const float* __restrict__ rel_pri,
    const float* __restrict__ nta, const float* __restrict__ nta1,
    const float* __restrict__ weightp,
    const float* __restrict__ qwqA, const float* __restrict__ kwkA,
    unsigned short* __restrict__ t_bf)
{
    __shared__ float tl[4][64][18];    // stride 18: writes<=2-way, b64 reads 4-way
    __shared__ float md2[4][64][35];   // stride 35: b32 reads 2-way (free)

    const int tid  = threadIdx.x;
    const int w    = tid >> 6;
    const int lane = tid & 63;
    const int h    = __builtin_amdgcn_readfirstlane((tid >> 6) + 4 * blockIdx.y);
    const int base = blockIdx.x * 64;
    const int dn   = base + lane;
    const int dtau = __builtin_amdgcn_readfirstlane(dn / NTP);  // uniform per block
    const int dl   = dn - dtau * NTP;
    const int m16  = lane & 15, quad = lane >> 4;

    // q A-fragments (f16). A[m][k]: m = node (l&15), k = (l>>4)*8+i; k>=16 zeroed
    // (B rows 16..31 are zero; also avoids OOB/garbage for h=7).
    half8 qf[4];
    #pragma unroll
    for (int g = 0; g < 4; g++) {
        half8 t;
        #pragma unroll
        for (int i = 0; i < 8; i++) t[i] = (_Float16)0.f;
        if (quad < 2) {
            const float* qp = q + (size_t)(base + g * 16 + m16) * 128 + h * 16 + quad * 8;
            #pragma unroll
            for (int i = 0; i < 8; i++) t[i] = (_Float16)qp[i];
        }
        qf[g] = t;
    }

    const float beta = 1.f / (1.f + expf(-weightp[0]));
    const float bl2e = beta * LOG2E;
    const float Pq   = bl2e * nta1[dtau] * qwqA[(size_t)dn * 8 + h];

    f32x4 thacc[4];
    #pragma unroll
    for (int g = 0; g < 4; g++) { f32x4 z = {0.f,0.f,0.f,0.f}; thacc[g] = z; }
    int nrel = 0;

    const int pb = PBASE[dtau], pc = PCNT[dtau];
    for (int p = 0; p < pc; p++) {
        const int pg = pb + p;
        int anyPair = 0;
        #pragma unroll
        for (int sub = 0; sub < 2; sub++) {
            const int r = PAIRS[pg][sub];
            const int b = r * NTP + dl;
            int cnt = counts[b];
            cnt = cnt < CAP ? cnt : CAP;
            float macc[16] = {};
            float den = 0.f;
            if (__any(cnt > 0)) {          // wave-uniform
                anyPair = 1;
                // ---- Aq via MFMA, transpose out through wave-private LDS ----
                half8 Ba = *(const half8*)(fragAtt + (((size_t)r * HH + h) << 9) + lane * 8);
                #pragma unroll
                for (int g = 0; g < 4; g++) {
                    f32x4 aq = {0.f, 0.f, 0.f, 0.f};
                    aq = __builtin_amdgcn_mfma_f32_16x16x32_f16(qf[g], Ba, aq, 0, 0, 0);
                    #pragma unroll
                    for (int i = 0; i < 4; i++)
                        tl[w][g * 16 + quad * 4 + i][m16] = aq[i];
                }
#if USE_FDOT2
                h2v Aqh[8];
                #pragma unroll
                for (int j = 0; j < 8; j++)
                    Aqh[j] = __builtin_bit_cast(h2v,
                        __builtin_amdgcn_cvt_pkrtz(tl[w][lane][2*j], tl[w][lane][2*j+1]));
#else
                float Aqf[16];
                #pragma unroll
                for (int d = 0; d < 16; d++) Aqf[d] = tl[w][lane][d];
#endif
                const float pri2 = rel_pri[r * HH + h] * (0.25f * LOG2E);
                const float S    = bl2e * nta[src_nt(r)];
                const int beg = b * CAP;
                int4 e0 = *(const int4*)(esrc16 + beg);
                int4 e1 = *(const int4*)(esrc16 + beg + 4);
                int4 e2 = make_int4(0,0,0,0), e3 = make_int4(0,0,0,0);
                if (__any(cnt > 8)) {
                    e2 = *(const int4*)(esrc16 + beg + 8);
                    e3 = *(const int4*)(esrc16 + beg + 12);
                }
                #pragma unroll
                for (int ch = 0; ch < 4; ch++) {
                    if (!__any(ch * 4 < cnt)) break;
                    const int4 cc = (ch == 0) ? e0 : (ch == 1) ? e1 : (ch == 2) ? e2 : e3;
                    #pragma unroll
                    for (int t = 0; t < 4; t++) {
                        const int j = ch * 4 + t;
                        if (j < cnt) {
                            const int sn = (t == 0) ? cc.x : (t == 1) ? cc.y : (t == 2) ? cc.z : cc.w;
                            const uint4* kp = (const uint4*)(kvh + (size_t)sn * 256 + h * 32);
                            uint4 u0 = kp[0], u1 = kp[1], u2 = kp[2], u3 = kp[3];
                            const float kwk = kwkA[(size_t)sn * 8 + h];
                            float a = 0.f;
#if USE_FDOT2
                            {
                                const unsigned int kw[8] = {u0.x,u0.y,u0.z,u0.w,u1.x,u1.y,u1.z,u1.w};
                                #pragma unroll
                                for (int i = 0; i < 8; i++)
                                    a = __builtin_amdgcn_fdot2(__builtin_bit_cast(h2v, kw[i]), Aqh[i], a, false);
                            }
#else
                            {
                                const unsigned int kw[8] = {u0.x,u0.y,u0.z,u0.w,u1.x,u1.y,u1.z,u1.w};
                                #pragma unroll
                                for (int i = 0; i < 8; i++) {
                                    h2v kk2 = __builtin_bit_cast(h2v, kw[i]);
                                    a += (float)kk2[0] * Aqf[2*i] + (float)kk2[1] * Aqf[2*i + 1];
                                }
                            }
#endif
                            float vv[16];
                            {
                                const unsigned int vw[8] = {u2.x,u2.y,u2.z,u2.w,u3.x,u3.y,u3.z,u3.w};
                                #pragma unroll
                                for (int i = 0; i < 8; i++) {
                                    h2v v2 = __builtin_bit_cast(h2v, vw[i]);
                                    vv[2*i] = (float)v2[0]; vv[2*i + 1] = (float)v2[1];
                                }
                            }
                            const float y  = fmaf(S, kwk, Pq);
                            const float na = fmaxf(y, 0.01f * y);      // leakyrelu, log2e folded
                            const float es = __builtin_amdgcn_exp2f(fmaf(a, pri2, na));
                            den += es;
                            #pragma unroll
                            for (int f = 0; f < 16; f++) macc[f] += es * vv[f];
                        }
                    }
                }
            }
            float inv = 0.f;
            if (cnt > 0) { inv = 1.0f / den; nrel++; }
            #pragma unroll
            for (int d = 0; d < 16; d++)
                md2[w][lane][sub * 16 + d] = macc[d] * inv;   // zeros when cnt==0
        }
        if (anyPair) {
            // ---- paired rel_msg apply: thacc += [md_a md_b] x [Ma; Mb] ----
            half8 Bm = *(const half8*)(fragMsgP + (((size_t)pg * HH + h) << 9) + lane * 8);
            #pragma unroll
            for (int g = 0; g < 4; g++) {
                const float* mp = &md2[w][g * 16 + m16][quad * 8];
                half8 am;
                #pragma unroll
                for (int i = 0; i < 8; i++) am[i] = (_Float16)mp[i];
                thacc[g] = __builtin_amdgcn_mfma_f32_16x16x32_f16(am, Bm, thacc[g], 0, 0, 0);
            }
        }
    }

    // output: transpose thacc (C layout) -> lane-major, scale 1/nrel, pack bf16
    #pragma unroll
    for (int g = 0; g < 4; g++) {
        #pragma unroll
        for (int i = 0; i < 4; i++)
            tl[w][g * 16 + quad * 4 + i][m16] = thacc[g][i];
    }
    const float innv = 1.f / (float)(nrel > 1 ? nrel : 1);
    float t16[16];
    #pragma unroll
    for (int f = 0; f < 16; f++) t16[f] = tl[w][lane][f] * innv;
    unsigned short* op = t_bf + (size_t)dn * 128 + h * 16;
    uint4 o0, o1;
    o0.x = bf2pack(t16[0],  t16[1]);
    o0.y = bf2pack(t16[2],  t16[3]);
    o0.z = bf2pack(t16[4],  t16[5]);
    o0.w = bf2pack(t16[6],  t16[7]);
    o1.x = bf2pack(t16[8],  t16[9]);
    o1.y = bf2pack(t16[10], t16[11]);
    o1.z = bf2pack(t16[12], t16[13]);
    o1.w = bf2pack(t16[14], t16[15]);
    *(uint4*)(op)     = o0;
    *(uint4*)(op + 8) = o1;
}

// ---------------- K4: output GEMM via bf16 MFMA + skip blend, vector epilogue ----
__global__ __launch_bounds__(256) void final_mfma(
    const unsigned short* __restrict__ t_bf,
    const unsigned short* __restrict__ wfrag,
    const float* __restrict__ ba, const float* __restrict__ skip,
    const float* __restrict__ x, float* __restrict__ out)
{
    __shared__ float os[4][16][132];
    const int rb   = blockIdx.x * 64;
    const int tau  = rb / NTP;
    const int w    = threadIdx.x >> 6;
    const int lane = threadIdx.x & 63;
    const int m    = lane & 15;
    const int quad = lane >> 4;

    short8 af[4];
    {
        const unsigned short* trow = t_bf + (size_t)(rb + w * 16 + m) * 128;
        #pragma unroll
        for (int s = 0; s < 4; s++)
            af[s] = *(const short8*)(trow + s * 32 + quad * 8);
    }

    #pragma unroll
    for (int n = 0; n < 8; n++) {
        float bb = ba[tau * 128 + n * 16 + m];
        f32x4 acc = {bb, bb, bb, bb};
        #pragma unroll
        for (int s = 0; s < 4; s++) {
            const int tile = 288 + tau * 32 + n * 4 + s;
            short8 bf = *(const short8*)(wfrag + (size_t)tile * 512 + lane * 8);
            acc = __builtin_amdgcn_mfma_f32_16x16x32_bf16(af[s], bf, acc, 0, 0, 0);
        }
        #pragma unroll
        for (int i = 0; i < 4; i++) os[w][quad * 4 + i][n * 16 + m] = acc[i];
    }
    __syncthreads();
    const float alpha = 1.f / (1.f + expf(-skip[tau]));
    const float oma   = 1.f - alpha;
    #pragma unroll
    for (int j = 0; j < 8; j++) {
        const int id = lane + 64 * j;
        const int row = id >> 5, c4 = id & 31;
        float4 t  = *(const float4*)(&os[w][row][c4 * 4]);
        const size_t base = (size_t)(rb + w * 16 + row) * 128 + c4 * 4;
        float4 xv = *(const float4*)(x + base);
        float4 o;
        o.x = t.x * alpha + xv.x * oma;
        o.y = t.y * alpha + xv.y * oma;
        o.z = t.z * alpha + xv.z * oma;
        o.w = t.w * alpha + xv.w * oma;
        *(float4*)(out + base) = o;
    }
}

extern "C" void kernel_launch(void* const* d_in, const int* in_sizes, int n_in,
                              void* d_out, int out_size, void* d_ws, size_t ws_size,
                              hipStream_t stream) {
    const float* x       = (const float*)d_in[0];
    const int*   src     = (const int*)  d_in[1];
    const int*   dst     = (const int*)  d_in[2];
    const float* Wk      = (const float*)d_in[3];
    const float* bk      = (const float*)d_in[4];
    const float* Wq      = (const float*)d_in[5];
    const float* bq      = (const float*)d_in[6];
    const float* Wv      = (const float*)d_in[7];
    const float* bv      = (const float*)d_in[8];
    const float* Wa      = (const float*)d_in[9];
    const float* ba      = (const float*)d_in[10];
    const float* rel_att = (const float*)d_in[11];
    const float* rel_msg = (const float*)d_in[12];
    const float* rel_pri = (const float*)d_in[13];
    const float* nta     = (const float*)d_in[14];
    const float* nta1    = (const float*)d_in[15];
    const float* skip    = (const float*)d_in[16];
    const float* weight  = (const float*)d_in[17];
    const float* attn_w  = (const float*)d_in[18];
    float* out = (float*)d_out;

    float* ws    = (float*)d_ws;
    float* q     = ws;                                       // NN*128 f32
    unsigned short* kvh = (unsigned short*)(q + (size_t)NN * 128);   // NN*256 f16
    unsigned short* t_bf = kvh + (size_t)NN * 256;           // NN*128 bf16
    int* counts  = (int*)(t_bf + (size_t)NN * 128);          // NB
    int* esrc16  = counts + NB;                              // NB*CAP
    unsigned short* wfrag = (unsigned short*)(esrc16 + (size_t)NB * CAP); // 384*512
    unsigned short* fragAtt  = wfrag + 384 * 512;            // 272*512 f16
    unsigned short* fragMsgP = fragAtt + 272 * 512;          // 136*512 f16
    float* qwqA  = (float*)(fragMsgP + 136 * 512);           // NN*8
    float* kwkA  = qwqA + (size_t)NN * 8;                    // NN*8

    prep_kernel<<<1063, 256, 0, stream>>>(Wk, Wq, Wv, Wa, rel_att, rel_msg,
                                          counts, wfrag, fragAtt, fragMsgP);
    work1<<<375 + NSCAT, 256, 0, stream>>>(x, bk, bq, bv, wfrag,
                                           src, dst, counts, esrc16, q, kvh,
                                           attn_w, qwqA, kwkA);
    edge_fused<<<dim3(NN / 64, 2), 256, 0, stream>>>(
        q, kvh, esrc16, counts, fragAtt, fragMsgP, rel_pri,
        nta, nta1, weight, qwqA, kwkA, t_bf);
    final_mfma<<<NN / 64, 256, 0, stream>>>(t_bf, wfrag, ba, skip, x, out);
}

// Round 4
// 192.019 us; speedup vs baseline: 1.1305x; 1.1305x over previous
//
#include <hip/hip_runtime.h>

#define NN   24000
#define NTP  8000
#define HH   8
#define DKK  16
#define RR   34
#define EPRN 10000
#define NE   (RR*EPRN)     // 340000
#define NB   (RR*NTP)      // 272000 buckets (r, dst_local)
#define CAP  16            // fixed bucket capacity; P(cnt>=16 | Poisson 1.25) ~ 1e-12
#define NSCAT ((NE+255)/256)   // 1329 scatter blocks
#define LOG2E 1.4426950408889634f

typedef short short8 __attribute__((ext_vector_type(8)));
typedef _Float16 half8 __attribute__((ext_vector_type(8)));
typedef float f32x4  __attribute__((ext_vector_type(4)));
typedef _Float16 h2v __attribute__((ext_vector_type(2)));

#if defined(__has_builtin)
# if __has_builtin(__builtin_amdgcn_fdot2)
#  define USE_FDOT2 1
# endif
#endif
#ifndef USE_FDOT2
# define USE_FDOT2 0
#endif

__device__ __forceinline__ int src_nt(int r){ return r<=9?0:(r<=21?1:2); }
__device__ __forceinline__ int dst_nt(int r){
    if (r<=2)  return 0;
    if (r<=6)  return 1;
    if (r<=9)  return 2;
    if (r<=13) return 0;
    if (r<=17) return 1;
    if (r<=21) return 2;
    if (r<=24) return 0;
    if (r<=28) return 1;
    return 2;
}

__device__ __forceinline__ unsigned short bf16rne(float a){
    unsigned int u = __float_as_uint(a);
    u += 0x7fffu + ((u >> 16) & 1u);
    return (unsigned short)(u >> 16);
}
__device__ __forceinline__ unsigned int bf2pack(float a, float b){
    unsigned int ua = __float_as_uint(a);
    unsigned int ub = __float_as_uint(b);
    ua += 0x7fffu + ((ua >> 16) & 1u);
    ub += 0x7fffu + ((ub >> 16) & 1u);
    return (ua >> 16) | (ub & 0xffff0000u);
}
__device__ __forceinline__ unsigned short f16bits(float a){
    _Float16 h = (_Float16)a;
    return __builtin_bit_cast(unsigned short, h);
}

// ---------------- K0: prep — zero counts + W B-frags + rel_att/rel_msg f16 B-frags
// wfrag tiles 0..287: t = ((tau*3+mat)*8+n)*4+s  (mat: 0=k,1=q,2=v); 288..383: Wa.
// fragAtt[rh][512]: B[k][n] = rel_att[r][h][n][k] for k<16, 0 for k>=16 (Aq MFMA).
// fragMsg[rh][512]: B[k][n] = rel_msg[r][h][k][n] for k<16, 0 for k>=16 (msg MFMA).
__global__ __launch_bounds__(256) void prep_kernel(
    const float* __restrict__ Wk, const float* __restrict__ Wq,
    const float* __restrict__ Wv, const float* __restrict__ Wa,
    const float* __restrict__ rel_att, const float* __restrict__ rel_msg,
    int* __restrict__ counts, unsigned short* __restrict__ wfrag,
    unsigned short* __restrict__ fragAtt, unsigned short* __restrict__ fragMsg)
{
    const int gid = blockIdx.x * 256 + threadIdx.x;
    if (gid < NB) counts[gid] = 0;
    const int wv   = threadIdx.x >> 6;
    const int lane = threadIdx.x & 63;
    const int m16  = lane & 15, quad = lane >> 4;
    if (blockIdx.x < 96) {
        const int tile = blockIdx.x * 4 + wv;   // 0..383
        const float* W;
        int s, n;
        if (tile < 288) {
            s = tile & 3;
            n = (tile >> 2) & 7;
            const int mat = (tile >> 5) % 3;
            const int tau = tile / 96;
            W = (mat == 0 ? Wk : (mat == 1 ? Wq : Wv)) + (size_t)tau * 16384;
        } else {
            const int t2 = tile - 288;
            s = t2 & 3;
            n = (t2 >> 2) & 7;
            const int tau = t2 >> 5;
            W = Wa + (size_t)tau * 16384;
        }
        const int k0  = s * 32 + quad * 8;
        const int col = n * 16 + m16;
        unsigned short* dstp = wfrag + (size_t)tile * 512 + lane * 8;
        #pragma unroll
        for (int i = 0; i < 8; i++)
            dstp[i] = bf16rne(W[(size_t)(k0 + i) * 128 + col]);
    } else if (blockIdx.x < 164) {
        const int rh = (blockIdx.x - 96) * 4 + wv;   // 0..271
        half8 v;
        #pragma unroll
        for (int i = 0; i < 8; i++) v[i] = (_Float16)0.f;
        if (quad < 2) {
            const float* p = rel_att + ((size_t)rh << 8) + m16 * 16 + quad * 8;
            #pragma unroll
            for (int i = 0; i < 8; i++) v[i] = (_Float16)p[i];
        }
        *(half8*)(fragAtt + ((size_t)rh << 9) + lane * 8) = v;
    } else if (blockIdx.x < 232) {
        const int rh = (blockIdx.x - 164) * 4 + wv;  // 0..271
        half8 v;
        #pragma unroll
        for (int i = 0; i < 8; i++) v[i] = (_Float16)0.f;
        if (quad < 2) {
            const float* Mp = rel_msg + ((size_t)rh << 8);
            #pragma unroll
            for (int i = 0; i < 8; i++) v[i] = (_Float16)Mp[(quad * 8 + i) * 16 + m16];
        }
        *(half8*)(fragMsg + ((size_t)rh << 9) + lane * 8) = v;
    }
}

// ---------------- K1: merged qkv-MFMA + edge scatter + qwq/kwk precompute ------
__global__ __launch_bounds__(256) void work1(
    const float* __restrict__ x,
    const float* __restrict__ bk, const float* __restrict__ bq,
    const float* __restrict__ bv,
    const unsigned short* __restrict__ wfrag,
    const int* __restrict__ src, const int* __restrict__ dst,
    int* __restrict__ counts, int* __restrict__ esrc16,
    float* __restrict__ qo, unsigned short* __restrict__ kvh,
    const float* __restrict__ attn_w,
    float* __restrict__ qwqA, float* __restrict__ kwkA)
{
    __shared__ float qs[4][16][132];
    __shared__ unsigned short ksh[4][16][264];

    if (blockIdx.x >= 375) {        // ---- scatter part ----
        int e = (blockIdx.x - 375) * 256 + threadIdx.x;
        if (e < NE) {
            int r = e / EPRN;
            int b = r * NTP + (dst[e] - dst_nt(r) * NTP);
            int pos = atomicAdd(&counts[b], 1);
            if (pos < CAP) esrc16[(size_t)b * CAP + pos] = src[e];
        }
        return;
    }

    // ---- qkv part ----
    const int rb   = blockIdx.x * 64;
    const int tau  = rb / NTP;          // 8000 % 64 == 0 -> uniform
    const int w    = threadIdx.x >> 6;
    const int lane = threadIdx.x & 63;
    const int m    = lane & 15;
    const int quad = lane >> 4;

    short8 af[4];
    {
        const float* xrow = x + (size_t)(rb + w * 16 + m) * 128;
        #pragma unroll
        for (int s = 0; s < 4; s++) {
            float4 f0 = *(const float4*)(xrow + s * 32 + quad * 8);
            float4 f1 = *(const float4*)(xrow + s * 32 + quad * 8 + 4);
            union { unsigned int u[4]; short8 v; } pk;
            pk.u[0] = bf2pack(f0.x, f0.y); pk.u[1] = bf2pack(f0.z, f0.w);
            pk.u[2] = bf2pack(f1.x, f1.y); pk.u[3] = bf2pack(f1.z, f1.w);
            af[s] = pk.v;
        }
    }

    #pragma unroll
    for (int mat = 0; mat < 3; mat++) {
        const float* bias = (mat == 0 ? bk : (mat == 1 ? bq : bv)) + tau * 128;
        #pragma unroll
        for (int n = 0; n < 8; n++) {
            float bb = bias[n * 16 + m];
            f32x4 acc = {bb, bb, bb, bb};
            #pragma unroll
            for (int s = 0; s < 4; s++) {
                const int tile = ((tau * 3 + mat) * 8 + n) * 4 + s;
                short8 bf = *(const short8*)(wfrag + (size_t)tile * 512 + lane * 8);
                acc = __builtin_amdgcn_mfma_f32_16x16x32_bf16(af[s], bf, acc, 0, 0, 0);
            }
            if (mat == 1) {
                #pragma unroll
                for (int i = 0; i < 4; i++) qs[w][quad * 4 + i][n * 16 + m] = acc[i];
            } else {
                const int off = n * 32 + (mat == 0 ? 0 : 16) + m;
                #pragma unroll
                for (int i = 0; i < 4; i++) ksh[w][quad * 4 + i][off] = f16bits(acc[i]);
            }
        }
        if (mat == 1) {
            __syncthreads();
            #pragma unroll
            for (int j = 0; j < 8; j++) {
                const int id = lane + 64 * j;
                const int row = id >> 5, c4 = id & 31;
                float4 v = *(const float4*)(&qs[w][row][c4 * 4]);
                *(float4*)(qo + (size_t)(rb + w * 16 + row) * 128 + c4 * 4) = v;
            }
        }
    }
    __syncthreads();
    #pragma unroll
    for (int j = 0; j < 8; j++) {
        const int id = lane + 64 * j;
        const int row = id >> 5, c8 = id & 31;
        uint4 u = *(const uint4*)(&ksh[w][row][c8 * 8]);
        *(uint4*)(kvh + (size_t)(rb + w * 16 + row) * 256 + c8 * 8) = u;
    }
    // epilogue: node-level qwq = q . wq, kwk = k . wk (per head) from LDS
    #pragma unroll
    for (int rep = 0; rep < 2; rep++) {
        const int idx = threadIdx.x + rep * 256;     // 0..511 = 64 rows x 8 heads
        const int row = idx >> 3, hh = idx & 7;
        const float* qrow = &qs[row >> 4][row & 15][hh * 16];
        const unsigned short* krow = &ksh[row >> 4][row & 15][hh * 32];
        float sq = 0.f, sk = 0.f;
        #pragma unroll
        for (int f = 0; f < 16; f++) {
            sq += qrow[f] * attn_w[f];
            sk += (float)__builtin_bit_cast(_Float16, krow[f]) * attn_w[16 + f];
        }
        qwqA[(size_t)(rb + row) * 8 + hh] = sq;
        kwkA[(size_t)(rb + row) * 8 + hh] = sk;
    }
}

// ---------------- K2: fused edge phase — Aq and rel_msg apply via f16 MFMA ------
// wave = 64 dst nodes x 1 head. Per relation: Aq = (64x16 q)x(16x16 A^T) as 4
// mfma_f32_16x16x32_f16 (K upper half zero). One wave-private f32 LDS scratch
// tl[64][18] (18.4 KB/block) serves all three transposes SEQUENTIALLY within an
// iteration (Aq C->lane-major; md lane-major->A-frag; final out). LDS ops of a
// wave are in-order -> no barriers (proven idiom from the 217us version).
__global__ __launch_bounds__(256) void edge_fused(
    const float* __restrict__ q, const unsigned short* __restrict__ kvh,
    const int* __restrict__ esrc16, const int* __restrict__ counts,
    const unsigned short* __restrict__ fragAtt,
    const unsigned short* __restrict__ fragMsg,
    const float* __restrict__ rel_pri,
    const float* __restrict__ nta, const float* __restrict__ nta1,
    const float* __restrict__ weightp,
    const float* __restrict__ qwqA, const float* __restrict__ kwkA,
    unsigned short* __restrict__ t_bf)
{
    __shared__ float tl[4][64][18];   // 18432 B; wave-private slices

    const int tid  = threadIdx.x;
    const int w    = tid >> 6;
    const int lane = tid & 63;
    const int h    = __builtin_amdgcn_readfirstlane((tid >> 6) + 4 * blockIdx.y);
    const int base = blockIdx.x * 64;
    const int dn   = base + lane;
    const int dtau = __builtin_amdgcn_readfirstlane(dn / NTP);  // uniform per block
    const int dl   = dn - dtau * NTP;
    const int m16  = lane & 15, quad = lane >> 4;

    // q A-fragments (f16). A[m][k]: m = node (l&15), k = (l>>4)*8+i; k>=16 zeroed
    half8 qf[4];
    #pragma unroll
    for (int g = 0; g < 4; g++) {
        half8 t;
        #pragma unroll
        for (int i = 0; i < 8; i++) t[i] = (_Float16)0.f;
        if (quad < 2) {
            const float* qp = q + (size_t)(base + g * 16 + m16) * 128 + h * 16 + quad * 8;
            #pragma unroll
            for (int i = 0; i < 8; i++) t[i] = (_Float16)qp[i];
        }
        qf[g] = t;
    }

    const float beta = 1.f / (1.f + expf(-weightp[0]));
    const float bl2e = beta * LOG2E;
    const float Pq   = bl2e * nta1[dtau] * qwqA[(size_t)dn * 8 + h];

    f32x4 thacc[4];
    #pragma unroll
    for (int g = 0; g < 4; g++) { f32x4 z = {0.f,0.f,0.f,0.f}; thacc[g] = z; }
    int nrel = 0;

    for (int r = 0; r < RR; r++) {
        if (dst_nt(r) != dtau) continue;      // uniform branch
        const int b   = r * NTP + dl;
        int cnt = counts[b];
        cnt = cnt < CAP ? cnt : CAP;
        if (!__any(cnt > 0)) continue;        // wave-uniform

        // ---- Aq via MFMA; C-layout (lane reg i = C[node quad*4+i][d m16]) ----
        half8 Ba = *(const half8*)(fragAtt + (((size_t)r * HH + h) << 9) + lane * 8);
        #pragma unroll
        for (int g = 0; g < 4; g++) {
            f32x4 aq = {0.f, 0.f, 0.f, 0.f};
            aq = __builtin_amdgcn_mfma_f32_16x16x32_f16(qf[g], Ba, aq, 0, 0, 0);
            #pragma unroll
            for (int i = 0; i < 4; i++)
                tl[w][g * 16 + quad * 4 + i][m16] = aq[i];
        }
#if USE_FDOT2
        h2v Aqh[8];
        #pragma unroll
        for (int j = 0; j < 8; j++)
            Aqh[j] = __builtin_bit_cast(h2v,
                __builtin_amdgcn_cvt_pkrtz(tl[w][lane][2*j], tl[w][lane][2*j+1]));
#else
        float Aqf[16];
        #pragma unroll
        for (int d = 0; d < 16; d++) Aqf[d] = tl[w][lane][d];
#endif

        const float pri2 = rel_pri[r * HH + h] * (0.25f * LOG2E);
        const float S    = bl2e * nta[src_nt(r)];
        const int beg = b * CAP;
        int4 e0 = *(const int4*)(esrc16 + beg);
        int4 e1 = *(const int4*)(esrc16 + beg + 4);
        int4 e2 = make_int4(0,0,0,0), e3 = make_int4(0,0,0,0);
        if (__any(cnt > 8)) {
            e2 = *(const int4*)(esrc16 + beg + 8);
            e3 = *(const int4*)(esrc16 + beg + 12);
        }

        float den = 0.f;
        float macc[16] = {};
        #pragma unroll
        for (int ch = 0; ch < 4; ch++) {
            if (!__any(ch * 4 < cnt)) break;
            const int4 cc = (ch == 0) ? e0 : (ch == 1) ? e1 : (ch == 2) ? e2 : e3;
            #pragma unroll
            for (int t = 0; t < 4; t++) {
                const int j = ch * 4 + t;
                if (j < cnt) {      // execz-skipped when no lane active
                    const int sn = (t == 0) ? cc.x : (t == 1) ? cc.y : (t == 2) ? cc.z : cc.w;
                    const uint4* kp = (const uint4*)(kvh + (size_t)sn * 256 + h * 32);
                    uint4 u0 = kp[0], u1 = kp[1], u2 = kp[2], u3 = kp[3];
                    const float kwk = kwkA[(size_t)sn * 8 + h];
                    float a = 0.f;
#if USE_FDOT2
                    {
                        const unsigned int kw[8] = {u0.x,u0.y,u0.z,u0.w,u1.x,u1.y,u1.z,u1.w};
                        #pragma unroll
                        for (int i = 0; i < 8; i++)
                            a = __builtin_amdgcn_fdot2(__builtin_bit_cast(h2v, kw[i]), Aqh[i], a, false);
                    }
#else
                    {
                        const unsigned int kw[8] = {u0.x,u0.y,u0.z,u0.w,u1.x,u1.y,u1.z,u1.w};
                        #pragma unroll
                        for (int i = 0; i < 8; i++) {
                            h2v kk2 = __builtin_bit_cast(h2v, kw[i]);
                            a += (float)kk2[0] * Aqf[2*i] + (float)kk2[1] * Aqf[2*i + 1];
                        }
                    }
#endif
                    float vv[16];
                    {
                        const unsigned int vw[8] = {u2.x,u2.y,u2.z,u2.w,u3.x,u3.y,u3.z,u3.w};
                        #pragma unroll
                        for (int i = 0; i < 8; i++) {
                            h2v v2 = __builtin_bit_cast(h2v, vw[i]);
                            vv[2*i] = (float)v2[0]; vv[2*i + 1] = (float)v2[1];
                        }
                    }
                    const float y  = fmaf(S, kwk, Pq);
                    const float na = fmaxf(y, 0.01f * y);      // leakyrelu, log2e folded
                    const float es = __builtin_amdgcn_exp2f(fmaf(a, pri2, na));
                    den += es;
                    #pragma unroll
                    for (int f = 0; f < 16; f++) macc[f] += es * vv[f];
                }
            }
        }

        float inv = 0.f;
        if (cnt > 0) { inv = 1.0f / den; nrel++; }
        // md lane-major f32 (reuses tl; Aq already consumed into registers)
        #pragma unroll
        for (int d = 0; d < 16; d++)
            tl[w][lane][d] = macc[d] * inv;     // zeros when cnt==0

        // msg MFMA: A[m=m16][k=quad*8+i] = md[node g*16+m16][d]; B rows k>=16
        // are zero, so quads 2/3 re-read quads 0/1 data (harmless, no NaN).
        half8 Bm = *(const half8*)(fragMsg + (((size_t)r * HH + h) << 9) + lane * 8);
        #pragma unroll
        for (int g = 0; g < 4; g++) {
            const float* mp = &tl[w][g * 16 + m16][(quad & 1) * 8];
            half8 am;
            #pragma unroll
            for (int i = 0; i < 8; i++) am[i] = (_Float16)mp[i];
            thacc[g] = __builtin_amdgcn_mfma_f32_16x16x32_f16(am, Bm, thacc[g], 0, 0, 0);
        }
    }

    // output: transpose thacc (C layout) -> lane-major via same LDS
    #pragma unroll
    for (int g = 0; g < 4; g++) {
        #pragma unroll
        for (int i = 0; i < 4; i++)
            tl[w][g * 16 + quad * 4 + i][m16] = thacc[g][i];
    }
    const float innv = 1.f / (float)(nrel > 1 ? nrel : 1);
    float t16[16];
    #pragma unroll
    for (int f = 0; f < 16; f++) t16[f] = tl[w][lane][f] * innv;
    unsigned short* op = t_bf + (size_t)dn * 128 + h * 16;
    uint4 o0, o1;
    o0.x = bf2pack(t16[0],  t16[1]);
    o0.y = bf2pack(t16[2],  t16[3]);
    o0.z = bf2pack(t16[4],  t16[5]);
    o0.w = bf2pack(t16[6],  t16[7]);
    o1.x = bf2pack(t16[8],  t16[9]);
    o1.y = bf2pack(t16[10], t16[11]);
    o1.z = bf2pack(t16[12], t16[13]);
    o1.w = bf2pack(t16[14], t16[15]);
    *(uint4*)(op)     = o0;
    *(uint4*)(op + 8) = o1;
}

// ---------------- K4: output GEMM via bf16 MFMA + skip blend, vector epilogue ----
__global__ __launch_bounds__(256) void final_mfma(
    const unsigned short* __restrict__ t_bf,
    const unsigned short* __restrict__ wfrag,
    const float* __restrict__ ba, const float* __restrict__ skip,
    const float* __restrict__ x, float* __restrict__ out)
{
    __shared__ float os[4][16][132];
    const int rb   = blockIdx.x * 64;
    const int tau  = rb / NTP;
    const int w    = threadIdx.x >> 6;
    const int lane = threadIdx.x & 63;
    const int m    = lane & 15;
    const int quad = lane >> 4;

    short8 af[4];
    {
        const unsigned short* trow = t_bf + (size_t)(rb + w * 16 + m) * 128;
        #pragma unroll
        for (int s = 0; s < 4; s++)
            af[s] = *(const short8*)(trow + s * 32 + quad * 8);
    }

    #pragma unroll
    for (int n = 0; n < 8; n++) {
        float bb = ba[tau * 128 + n * 16 + m];
        f32x4 acc = {bb, bb, bb, bb};
        #pragma unroll
        for (int s = 0; s < 4; s++) {
            const int tile = 288 + tau * 32 + n * 4 + s;
            short8 bf = *(const short8*)(wfrag + (size_t)tile * 512 + lane * 8);
            acc = __builtin_amdgcn_mfma_f32_16x16x32_bf16(af[s], bf, acc, 0, 0, 0);
        }
        #pragma unroll
        for (int i = 0; i < 4; i++) os[w][quad * 4 + i][n * 16 + m] = acc[i];
    }
    __syncthreads();
    const float alpha = 1.f / (1.f + expf(-skip[tau]));
    const float oma   = 1.f - alpha;
    #pragma unroll
    for (int j = 0; j < 8; j++) {
        const int id = lane + 64 * j;
        const int row = id >> 5, c4 = id & 31;
        float4 t  = *(const float4*)(&os[w][row][c4 * 4]);
        const size_t base = (size_t)(rb + w * 16 + row) * 128 + c4 * 4;
        float4 xv = *(const float4*)(x + base);
        float4 o;
        o.x = t.x * alpha + xv.x * oma;
        o.y = t.y * alpha + xv.y * oma;
        o.z = t.z * alpha + xv.z * oma;
        o.w = t.w * alpha + xv.w * oma;
        *(float4*)(out + base) = o;
    }
}

extern "C" void kernel_launch(void* const* d_in, const int* in_sizes, int n_in,
                              void* d_out, int out_size, void* d_ws, size_t ws_size,
                              hipStream_t stream) {
    const float* x       = (const float*)d_in[0];
    const int*   src     = (const int*)  d_in[1];
    const int*   dst     = (const int*)  d_in[2];
    const float* Wk      = (const float*)d_in[3];
    const float* bk      = (const float*)d_in[4];
    const float* Wq      = (const float*)d_in[5];
    const float* bq      = (const float*)d_in[6];
    const float* Wv      = (const float*)d_in[7];
    const float* bv      = (const float*)d_in[8];
    const float* Wa      = (const float*)d_in[9];
    const float* ba      = (const float*)d_in[10];
    const float* rel_att = (const float*)d_in[11];
    const float* rel_msg = (const float*)d_in[12];
    const float* rel_pri = (const float*)d_in[13];
    const float* nta     = (const float*)d_in[14];
    const float* nta1    = (const float*)d_in[15];
    const float* skip    = (const float*)d_in[16];
    const float* weight  = (const float*)d_in[17];
    const float* attn_w  = (const float*)d_in[18];
    float* out = (float*)d_out;

    float* ws    = (float*)d_ws;
    float* q     = ws;                                       // NN*128 f32
    unsigned short* kvh = (unsigned short*)(q + (size_t)NN * 128);   // NN*256 f16
    unsigned short* t_bf = kvh + (size_t)NN * 256;           // NN*128 bf16
    int* counts  = (int*)(t_bf + (size_t)NN * 128);          // NB
    int* esrc16  = counts + NB;                              // NB*CAP
    unsigned short* wfrag = (unsigned short*)(esrc16 + (size_t)NB * CAP); // 384*512
    unsigned short* fragAtt = wfrag + 384 * 512;             // 272*512 f16
    unsigned short* fragMsg = fragAtt + 272 * 512;           // 272*512 f16
    float* qwqA  = (float*)(fragMsg + 272 * 512);            // NN*8
    float* kwkA  = qwqA + (size_t)NN * 8;                    // NN*8

    prep_kernel<<<1063, 256, 0, stream>>>(Wk, Wq, Wv, Wa, rel_att, rel_msg,
                                          counts, wfrag, fragAtt, fragMsg);
    work1<<<375 + NSCAT, 256, 0, stream>>>(x, bk, bq, bv, wfrag,
                                           src, dst, counts, esrc16, q, kvh,
                                           attn_w, qwqA, kwkA);
    edge_fused<<<dim3(NN / 64, 2), 256, 0, stream>>>(
        q, kvh, esrc16, counts, fragAtt, fragMsg, rel_pri,
        nta, nta1, weight, qwqA, kwkA, t_bf);
    final_mfma<<<NN / 64, 256, 0, stream>>>(t_bf, wfrag, ba, skip, x, out);
}